// Round 7
// baseline (274.231 us; speedup 1.0000x reference)
//
#include <hip/hip_runtime.h>
#include <hip/hip_bf16.h>

typedef __attribute__((ext_vector_type(8))) short short8;   // 8 bf16 = 4 VGPRs
typedef __attribute__((ext_vector_type(4))) float float4v;  // 4 fp32 acc
typedef __hip_bfloat16 bf16;

#define MFMA16(a, b, c) __builtin_amdgcn_mfma_f32_16x16x32_bf16((a), (b), (c), 0, 0, 0)

static __device__ __forceinline__ short8 load8(const bf16* p) {
    return *reinterpret_cast<const short8*>(p);
}
static __device__ __forceinline__ unsigned short bfu(float x) {
    union { bf16 b; unsigned short u; } c; c.b = __float2bfloat16(x); return c.u;
}
static __device__ __forceinline__ unsigned pack2(float lo, float hi) {
    return ((unsigned)bfu(hi) << 16) | bfu(lo);
}
static __device__ __forceinline__ short bf_bits(float x) {
    union { bf16 b; short u; } c; c.b = __float2bfloat16(x); return c.u;
}
static __device__ __forceinline__ short8 cvt8(float4 a, float4 b) {
    short8 r;
    r[0] = bf_bits(a.x); r[1] = bf_bits(a.y); r[2] = bf_bits(a.z); r[3] = bf_bits(a.w);
    r[4] = bf_bits(b.x); r[5] = bf_bits(b.y); r[6] = bf_bits(b.z); r[7] = bf_bits(b.w);
    return r;
}

// async global -> LDS, 16B per lane. LDS dest = wave-uniform base + lane*16.
typedef const __attribute__((address_space(1))) unsigned int* gp1;
typedef __attribute__((address_space(3))) unsigned int* lp3;
static __device__ __forceinline__ void async16(const void* g, void* l) {
    __builtin_amdgcn_global_load_lds((gp1)g, (lp3)l, 16, 0, 0);
}

// ---------------------------------------------------------------------------
// Transpose + convert 1024x1024 fp32 W[k][n] -> bf16 Wt[n][k].
// ---------------------------------------------------------------------------
__global__ __launch_bounds__(256) void transpose_qkv(
    const float* __restrict__ Wq, const float* __restrict__ Wk,
    const float* __restrict__ Wv, bf16* __restrict__ out_base)
{
    __shared__ bf16 tile[64][65];
    const float* in = (blockIdx.z == 0) ? Wq : (blockIdx.z == 1) ? Wk : Wv;
    bf16* out = out_base + (size_t)blockIdx.z * 1048576;
    int tx = threadIdx.x, ty = threadIdx.y;
    int bx = blockIdx.x * 64, by = blockIdx.y * 64;
    for (int i = ty; i < 64; i += 4)
        tile[i][tx] = __float2bfloat16(in[(size_t)(by + i) * 1024 + bx + tx]);
    __syncthreads();
    for (int i = ty; i < 64; i += 4)
        out[(size_t)(bx + i) * 1024 + by + tx] = tile[tx][i];
}

__global__ __launch_bounds__(256) void transpose_one(
    const float* __restrict__ in, bf16* __restrict__ out)
{
    __shared__ bf16 tile[64][65];
    int tx = threadIdx.x, ty = threadIdx.y;
    int bx = blockIdx.x * 64, by = blockIdx.y * 64;
    for (int i = ty; i < 64; i += 4)
        tile[i][tx] = __float2bfloat16(in[(size_t)(by + i) * 1024 + bx + tx]);
    __syncthreads();
    for (int i = ty; i < 64; i += 4)
        out[(size_t)(bx + i) * 1024 + by + tx] = tile[tx][i];
}

// ---------------------------------------------------------------------------
// QKV projection GEMM, pipelined dbuf + XCD swizzle.
// 1-D grid 768. xcd = wg%8; the 8 n-blocks sharing one A-tile (z,m) are
// consecutive-by-8 => same XCD, co-dispatched => A-tile fetched once into
// that XCD's L2 (was: spread over 8 XCDs, 8x HBM re-fetch, FETCH=206MB).
// Tile 128x128, BK=32; A staged fp32 (cvt at frag read).
// ---------------------------------------------------------------------------
__global__ __launch_bounds__(256, 3) void qkv_gemm(
    const float* __restrict__ Xq, const float* __restrict__ Xk,
    const float* __restrict__ Xv, const bf16* __restrict__ Wt_all,
    const float* __restrict__ bq, const float* __restrict__ bk,
    const float* __restrict__ bv,
    bf16* __restrict__ outq, bf16* __restrict__ outk, bf16* __restrict__ outv)
{
    __shared__ float As[2][128 * 32];   // 2 x 16KB
    __shared__ bf16  Bs[2][128 * 32];   // 2 x 8KB

    int wg = blockIdx.x;
    int xcd = wg & 7;
    int jj = wg >> 3;                  // 0..95
    int grp = xcd * 12 + (jj >> 3);    // 0..95
    int z = grp >> 5;                  // 0..2
    int m_blk = grp & 31;
    int n_blk = jj & 7;

    const float* X    = (z == 0) ? Xq : (z == 1) ? Xk : Xv;
    const float* bias = (z == 0) ? bq : (z == 1) ? bk : bv;
    const bf16*  Wt   = Wt_all + (size_t)z * 1048576;
    bf16*        out  = (z == 0) ? outq : (z == 1) ? outk : outv;
    bool vmode = (z == 2);

    int tid = threadIdx.x;
    int w = tid >> 6, lane = tid & 63, l16 = lane & 15, quad = lane >> 4;
    int m_base = m_blk * 128, n_base = n_blk * 128;

    int ra = lane >> 3;
    int sa = (lane & 7) ^ (ra & 7);
    int rb = lane >> 2;
    int sb = (lane & 3) ^ (rb & 3);
    const float* Asrc = X  + (size_t)(m_base + w * 8 + ra) * 1024 + sa * 4;
    const bf16*  Bsrc = Wt + (size_t)(n_base + w * 16 + rb) * 1024 + sb * 8;

    int wm = (w & 1) * 64, wn = (w >> 1) * 64;

    float4v zero = {0.f, 0.f, 0.f, 0.f};
    float4v acc[4][4];
    #pragma unroll
    for (int mi = 0; mi < 4; ++mi)
        #pragma unroll
        for (int nj = 0; nj < 4; ++nj) acc[mi][nj] = zero;

    #pragma unroll
    for (int p = 0; p < 4; ++p)
        async16(Asrc + (size_t)p * 32 * 1024, (char*)As[0] + w * 1024 + p * 4096);
    #pragma unroll
    for (int p = 0; p < 2; ++p)
        async16(Bsrc + (size_t)p * 64 * 1024, (char*)Bs[0] + w * 1024 + p * 4096);
    __syncthreads();

    for (int it = 0; it < 32; ++it) {
        int cur = it & 1, nxt = cur ^ 1;
        int kn = ((it + 1) & 31) * 32;            // wrap: harmless re-stage

        #pragma unroll
        for (int p = 0; p < 4; ++p)
            async16(Asrc + (size_t)p * 32 * 1024 + kn,
                    (char*)As[nxt] + w * 1024 + p * 4096);
        #pragma unroll
        for (int p = 0; p < 2; ++p)
            async16(Bsrc + (size_t)p * 64 * 1024 + kn,
                    (char*)Bs[nxt] + w * 1024 + p * 4096);

        short8 af[4], bf[4];
        #pragma unroll
        for (int mi = 0; mi < 4; ++mi) {
            const float* rp = As[cur] + (wm + mi * 16 + l16) * 32;
            float4 f0 = *(const float4*)(rp + (((quad * 2)     ^ (l16 & 7)) << 2));
            float4 f1 = *(const float4*)(rp + (((quad * 2 + 1) ^ (l16 & 7)) << 2));
            af[mi] = cvt8(f0, f1);
        }
        #pragma unroll
        for (int nj = 0; nj < 4; ++nj) {
            const bf16* rp = Bs[cur] + (wn + nj * 16 + l16) * 32;
            bf[nj] = load8(rp + ((quad ^ (l16 & 3)) << 3));
        }
        #pragma unroll
        for (int mi = 0; mi < 4; ++mi)
            #pragma unroll
            for (int nj = 0; nj < 4; ++nj)
                acc[mi][nj] = MFMA16(af[mi], bf[nj], acc[mi][nj]);
        __syncthreads();
    }

    float bsv[4];
    #pragma unroll
    for (int nj = 0; nj < 4; ++nj)
        bsv[nj] = bias[n_base + wn + nj * 16 + l16];

    #pragma unroll
    for (int mi = 0; mi < 4; ++mi) {
        #pragma unroll
        for (int nj = 0; nj < 4; ++nj) {
            int n = n_base + wn + nj * 16 + l16;
            int h = n >> 6, dk = n & 63;
            int m0 = m_base + wm + mi * 16 + quad * 4;
            int b = m0 >> 11, s0 = m0 & 2047;
            if (vmode) {
                float v0 = acc[mi][nj][0] + bsv[nj];
                float v1 = acc[mi][nj][1] + bsv[nj];
                float v2 = acc[mi][nj][2] + bsv[nj];
                float v3 = acc[mi][nj][3] + bsv[nj];
                uint2 pv; pv.x = pack2(v0, v1); pv.y = pack2(v2, v3);
                size_t idx = ((size_t)(b * 16 + h) * 64 + dk) * 2048 + s0;
                *reinterpret_cast<uint2*>(out + idx) = pv;
            } else {
                #pragma unroll
                for (int r = 0; r < 4; ++r) {
                    size_t idx = (((size_t)(b * 16 + h) * 2048 + s0 + r) * 64 + dk);
                    out[idx] = __float2bfloat16(acc[mi][nj][r] + bsv[nj]);
                }
            }
        }
    }
}

// ---------------------------------------------------------------------------
// Output projection: out[4096,1024] fp32 = A(bf16) @ Wo + bo.
// 1-D grid 512, XCD swizzle: the 16 n-blocks sharing one A-tile -> same XCD.
// Tile 128(M)x64(N), pipelined dbuf.
// ---------------------------------------------------------------------------
__global__ __launch_bounds__(256, 2) void out_gemm(
    const bf16* __restrict__ A, const bf16* __restrict__ Wt,
    const float* __restrict__ bias, float* __restrict__ out)
{
    __shared__ bf16 As[2][128 * 32];   // 2 x 8KB
    __shared__ bf16 Bs[2][64 * 32];    // 2 x 4KB

    int wg = blockIdx.x;
    int xcd = wg & 7;
    int jj = wg >> 3;                  // 0..63
    int m_blk = xcd * 4 + (jj >> 4);   // 0..31
    int n_blk = jj & 15;

    int tid = threadIdx.x;
    int w = tid >> 6, lane = tid & 63, l16 = lane & 15, quad = lane >> 4;
    int m_base = m_blk * 128, n_base = n_blk * 64;

    int rr = lane >> 2;
    int ss = (lane & 3) ^ (rr & 3);
    const bf16* Asrc = A  + (size_t)(m_base + w * 16 + rr) * 1024 + ss * 8;
    const bf16* Bsrc = Wt + (size_t)(n_base + w * 16 + rr) * 1024 + ss * 8;

    int wm = (w & 1) * 64, wn = (w >> 1) * 32;

    float4v zero = {0.f, 0.f, 0.f, 0.f};
    float4v acc[4][2];
    #pragma unroll
    for (int mi = 0; mi < 4; ++mi)
        #pragma unroll
        for (int nj = 0; nj < 2; ++nj) acc[mi][nj] = zero;

    #pragma unroll
    for (int p = 0; p < 2; ++p)
        async16(Asrc + (size_t)p * 64 * 1024, (char*)As[0] + w * 1024 + p * 4096);
    async16(Bsrc, (char*)Bs[0] + w * 1024);
    __syncthreads();

    for (int it = 0; it < 32; ++it) {
        int cur = it & 1, nxt = cur ^ 1;
        int kn = ((it + 1) & 31) * 32;

        #pragma unroll
        for (int p = 0; p < 2; ++p)
            async16(Asrc + (size_t)p * 64 * 1024 + kn,
                    (char*)As[nxt] + w * 1024 + p * 4096);
        async16(Bsrc + kn, (char*)Bs[nxt] + w * 1024);

        short8 af[4], bf[2];
        #pragma unroll
        for (int mi = 0; mi < 4; ++mi) {
            const bf16* rp = As[cur] + (wm + mi * 16 + l16) * 32;
            af[mi] = load8(rp + ((quad ^ (l16 & 3)) << 3));
        }
        #pragma unroll
        for (int nj = 0; nj < 2; ++nj) {
            const bf16* rp = Bs[cur] + (wn + nj * 16 + l16) * 32;
            bf[nj] = load8(rp + ((quad ^ (l16 & 3)) << 3));
        }
        #pragma unroll
        for (int mi = 0; mi < 4; ++mi)
            #pragma unroll
            for (int nj = 0; nj < 2; ++nj)
                acc[mi][nj] = MFMA16(af[mi], bf[nj], acc[mi][nj]);
        __syncthreads();
    }

    float bsv[2];
    #pragma unroll
    for (int nj = 0; nj < 2; ++nj)
        bsv[nj] = bias[n_base + wn + nj * 16 + l16];

    #pragma unroll
    for (int mi = 0; mi < 4; ++mi)
        #pragma unroll
        for (int nj = 0; nj < 2; ++nj) {
            int n = n_base + wn + nj * 16 + l16;
            int m0 = m_base + wm + mi * 16 + quad * 4;
            #pragma unroll
            for (int r = 0; r < 4; ++r)
                out[(size_t)(m0 + r) * 1024 + n] = acc[mi][nj][r] + bsv[nj];
        }
}

// ---------------------------------------------------------------------------
// Flash attention, S-transposed. Single-buffered K/V staging at 4 blocks/CU
// (16 waves/CU): 4 independent barrier groups overlap the staging drains
// (dbuf at 2 blocks/CU measured no better than single at 2 — occupancy is
// the lever). Mask folded to a 64-bit ballot bitmask (256B LDS, was 8KB
// float bias); wave-uniform m64==~0 test skips all masking VALU.
// XCD swizzle: the 16 q-blocks sharing one head's K/V -> same XCD.
// ---------------------------------------------------------------------------
__global__ __launch_bounds__(256, 4) void attn_fused(
    const bf16* __restrict__ Qm, const bf16* __restrict__ Km,
    const bf16* __restrict__ Vt, const int* __restrict__ mask,
    bf16* __restrict__ Oout)
{
    __shared__ __align__(16) bf16 Kc[64 * 64];     // 8KB [key][d] swizzled
    __shared__ __align__(16) bf16 Vc[64 * 64];     // 8KB [d][key] swizzled
    __shared__ __align__(16) bf16 P[4][32 * 72];   // 18KB per-wave P^T
    __shared__ unsigned long long maskb[32];       // 256B: bit k of [i] = mask[i*64+k]

    int tid = threadIdx.x;
    int w = tid >> 6, lane = tid & 63, l16 = lane & 15, quad = lane >> 4;
    int wg = blockIdx.x;
    int xcd = wg & 7;
    int jj = wg >> 3;                  // 0..63
    int bh = xcd * 4 + (jj >> 4);      // 0..31
    int qg = jj & 15;
    int b = bh >> 4, h = bh & 15;
    int tile0 = (qg * 4 + w) * 2;

    // build mask bitmask: wave w covers keys w*512 .. w*512+511
    const int* mb = mask + b * 2048;
    #pragma unroll
    for (int i = 0; i < 8; ++i) {
        unsigned long long bal = __ballot(mb[w * 512 + i * 64 + lane] != 0);
        if (lane == 0) maskb[w * 8 + i] = bal;
    }

    short8 bQ[2][2];
    #pragma unroll
    for (int qi = 0; qi < 2; ++qi) {
        const bf16* Qb = Qm + ((size_t)bh * 2048 + (size_t)(tile0 + qi) * 16) * 64;
        bQ[qi][0] = load8(Qb + l16 * 64 + quad * 8);
        bQ[qi][1] = load8(Qb + l16 * 64 + 32 + quad * 8);
    }

    int r8 = lane >> 3;
    int sl = (lane & 7) ^ (r8 & 7);
    const bf16* Ksrc = Km + (size_t)bh * 2048 * 64 + (size_t)(w * 8 + r8) * 64 + sl * 8;
    const bf16* Vsrc = Vt + (size_t)bh * 64 * 2048 + (size_t)(w * 8 + r8) * 2048 + sl * 8;
    char* Kdst = (char*)Kc + w * 1024;
    char* Vdst = (char*)Vc + w * 1024;

    bf16* Pw = &P[w][0];
    int sw = l16 & 7;

    float4v zero = {0.f, 0.f, 0.f, 0.f};
    float4v Oacc[2][4];
    #pragma unroll
    for (int qi = 0; qi < 2; ++qi)
        #pragma unroll
        for (int g = 0; g < 4; ++g) Oacc[qi][g] = zero;
    float lsum[2] = {0.f, 0.f};
    const float C = 0.18033688f;                   // log2(e)/8

    for (int it = 0; it < 32; ++it) {
        int kt = it * 64;
        async16(Ksrc + (size_t)kt * 64, Kdst);
        async16(Ksrc + (size_t)(kt + 32) * 64, Kdst + 4096);
        async16(Vsrc + kt, Vdst);
        async16(Vsrc + (size_t)32 * 2048 + kt, Vdst + 4096);
        __syncthreads();   // staging landed (also publishes maskb on it==0)

        unsigned long long m64 = maskb[it];
        bool full = (m64 == ~0ull);

        // --- S^T = K Q^T : 4 key-tiles x 2 q-tiles ---
        float4v S[2][4];
        #pragma unroll
        for (int kj = 0; kj < 4; ++kj) {
            const bf16* kr = Kc + (kj * 16 + l16) * 64;
            short8 a0 = load8(kr + (((0 + quad) ^ sw) << 3));
            short8 a1 = load8(kr + (((4 + quad) ^ sw) << 3));
            #pragma unroll
            for (int qi = 0; qi < 2; ++qi) {
                float4v s = zero;
                s = MFMA16(a0, bQ[qi][0], s);
                s = MFMA16(a1, bQ[qi][1], s);
                S[qi][kj] = s;
            }
        }

        // --- p = exp2(S*C), mask-zero, per-lane key-sum, P^T -> LDS ---
        #pragma unroll
        for (int kj = 0; kj < 4; ++kj) {
            unsigned m4 = (unsigned)(m64 >> (kj * 16 + quad * 4)) & 0xFu;
            #pragma unroll
            for (int qi = 0; qi < 2; ++qi) {
                float p[4];
                #pragma unroll
                for (int r = 0; r < 4; ++r)
                    p[r] = __builtin_amdgcn_exp2f(S[qi][kj][r] * C);
                if (!full) {
                    #pragma unroll
                    for (int r = 0; r < 4; ++r)
                        p[r] = ((m4 >> r) & 1u) ? p[r] : 0.f;
                }
                lsum[qi] += (p[0] + p[1]) + (p[2] + p[3]);
                uint2 pw; pw.x = pack2(p[0], p[1]); pw.y = pack2(p[2], p[3]);
                *reinterpret_cast<uint2*>(
                    &Pw[(qi * 16 + l16) * 72 + kj * 16 + quad * 4]) = pw;
            }
        }

        // --- O += P V (per-wave LDS round trip; in-order DS, no barrier) ---
        short8 ap[2][2];
        #pragma unroll
        for (int qi = 0; qi < 2; ++qi) {
            ap[qi][0] = load8(&Pw[(qi * 16 + l16) * 72 + quad * 8]);
            ap[qi][1] = load8(&Pw[(qi * 16 + l16) * 72 + 32 + quad * 8]);
        }
        #pragma unroll
        for (int g = 0; g < 4; ++g) {
            const bf16* vr = Vc + (g * 16 + l16) * 64;
            short8 v0 = load8(vr + (((0 + quad) ^ sw) << 3));
            short8 v1 = load8(vr + (((4 + quad) ^ sw) << 3));
            #pragma unroll
            for (int qi = 0; qi < 2; ++qi) {
                Oacc[qi][g] = MFMA16(ap[qi][0], v0, Oacc[qi][g]);
                Oacc[qi][g] = MFMA16(ap[qi][1], v1, Oacc[qi][g]);
            }
        }
        __syncthreads();   // all waves done reading Kc/Vc before next stage
    }

    #pragma unroll
    for (int qi = 0; qi < 2; ++qi) {
        float ls = lsum[qi];
        ls += __shfl_xor(ls, 16, 64);
        ls += __shfl_xor(ls, 32, 64);
        #pragma unroll
        for (int r = 0; r < 4; ++r) {
            float linv = 1.f / __shfl(ls, quad * 4 + r, 64);
            int srow = (tile0 + qi) * 16 + quad * 4 + r;
            size_t base = ((size_t)b * 2048 + srow) * 1024 + h * 64;
            #pragma unroll
            for (int g = 0; g < 4; ++g)
                Oout[base + g * 16 + l16] = __float2bfloat16(Oacc[qi][g][r] * linv);
        }
    }
}

// ---------------------------------------------------------------------------
// Workspace (16 MB of d_ws; d_out doubles as scratch):
//   ws[ 0.. 8): vb [B,H,Dk,S]          -> then Wo^T at [0..2) after attn
//   ws[ 8..14): Wq^T, Wk^T, Wv^T (dead after qkv_gemm)
//   ws[ 8..16): aout [B,S,1024] bf16 (over dead Wq/k/v^T)
//   d_out[0..8): qb, [8..16): kb (dead before out_gemm overwrites d_out)
// ---------------------------------------------------------------------------
extern "C" void kernel_launch(void* const* d_in, const int* in_sizes, int n_in,
                              void* d_out, int out_size, void* d_ws, size_t ws_size,
                              hipStream_t stream) {
    const float* query = (const float*)d_in[0];
    const float* key   = (const float*)d_in[1];
    const float* value = (const float*)d_in[2];
    const int*   mask  = (const int*)d_in[3];
    const float* Wq = (const float*)d_in[4];
    const float* bq = (const float*)d_in[5];
    const float* Wk = (const float*)d_in[6];
    const float* bk = (const float*)d_in[7];
    const float* Wv = (const float*)d_in[8];
    const float* bv = (const float*)d_in[9];
    const float* Wo = (const float*)d_in[10];
    const float* bo = (const float*)d_in[11];

    char* ws = (char*)d_ws;
    const size_t MB = 1024 * 1024;
    bf16* vb     = (bf16*)ws;                 // 8 MB
    bf16* Wt_all = (bf16*)(ws + 8 * MB);      // 3 x 2 MB
    bf16* aout   = (bf16*)(ws + 8 * MB);      // 8 MB (after Wq/k/v^T dead)
    bf16* WtO    = (bf16*)ws;                 // 2 MB (after vb dead)
    bf16* qb     = (bf16*)d_out;
    bf16* kb     = (bf16*)((char*)d_out + 8 * MB);
    float* out   = (float*)d_out;

    transpose_qkv<<<dim3(16, 16, 3), dim3(64, 4), 0, stream>>>(Wq, Wk, Wv, Wt_all);

    qkv_gemm<<<dim3(768), 256, 0, stream>>>(
        query, key, value, Wt_all, bq, bk, bv, qb, kb, vb);

    attn_fused<<<dim3(512), 256, 0, stream>>>(qb, kb, vb, mask, aout);

    transpose_one<<<dim3(16, 16), dim3(64, 4), 0, stream>>>(Wo, WtO);

    out_gemm<<<dim3(512), 256, 0, stream>>>(aout, WtO, bo, out);
}

// Round 8
// 251.224 us; speedup vs baseline: 1.0916x; 1.0916x over previous
//
#include <hip/hip_runtime.h>
#include <hip/hip_bf16.h>

typedef __attribute__((ext_vector_type(8))) short short8;   // 8 bf16 = 4 VGPRs
typedef __attribute__((ext_vector_type(4))) float float4v;  // 4 fp32 acc
typedef __hip_bfloat16 bf16;

#define MFMA16(a, b, c) __builtin_amdgcn_mfma_f32_16x16x32_bf16((a), (b), (c), 0, 0, 0)

static __device__ __forceinline__ short8 load8(const bf16* p) {
    return *reinterpret_cast<const short8*>(p);
}
static __device__ __forceinline__ unsigned short bfu(float x) {
    union { bf16 b; unsigned short u; } c; c.b = __float2bfloat16(x); return c.u;
}
static __device__ __forceinline__ unsigned pack2(float lo, float hi) {
    return ((unsigned)bfu(hi) << 16) | bfu(lo);
}
static __device__ __forceinline__ short bf_bits(float x) {
    union { bf16 b; short u; } c; c.b = __float2bfloat16(x); return c.u;
}
static __device__ __forceinline__ short8 cvt8(float4 a, float4 b) {
    short8 r;
    r[0] = bf_bits(a.x); r[1] = bf_bits(a.y); r[2] = bf_bits(a.z); r[3] = bf_bits(a.w);
    r[4] = bf_bits(b.x); r[5] = bf_bits(b.y); r[6] = bf_bits(b.z); r[7] = bf_bits(b.w);
    return r;
}

// async global -> LDS, 16B per lane. LDS dest = wave-uniform base + lane*16.
typedef const __attribute__((address_space(1))) unsigned int* gp1;
typedef __attribute__((address_space(3))) unsigned int* lp3;
static __device__ __forceinline__ void async16(const void* g, void* l) {
    __builtin_amdgcn_global_load_lds((gp1)g, (lp3)l, 16, 0, 0);
}

// ---------------------------------------------------------------------------
// Transpose + convert 1024x1024 fp32 W[k][n] -> bf16 Wt[n][k].
// ---------------------------------------------------------------------------
__global__ __launch_bounds__(256) void transpose_qkv(
    const float* __restrict__ Wq, const float* __restrict__ Wk,
    const float* __restrict__ Wv, bf16* __restrict__ out_base)
{
    __shared__ bf16 tile[64][65];
    const float* in = (blockIdx.z == 0) ? Wq : (blockIdx.z == 1) ? Wk : Wv;
    bf16* out = out_base + (size_t)blockIdx.z * 1048576;
    int tx = threadIdx.x, ty = threadIdx.y;
    int bx = blockIdx.x * 64, by = blockIdx.y * 64;
    for (int i = ty; i < 64; i += 4)
        tile[i][tx] = __float2bfloat16(in[(size_t)(by + i) * 1024 + bx + tx]);
    __syncthreads();
    for (int i = ty; i < 64; i += 4)
        out[(size_t)(bx + i) * 1024 + by + tx] = tile[tx][i];
}

__global__ __launch_bounds__(256) void transpose_one(
    const float* __restrict__ in, bf16* __restrict__ out)
{
    __shared__ bf16 tile[64][65];
    int tx = threadIdx.x, ty = threadIdx.y;
    int bx = blockIdx.x * 64, by = blockIdx.y * 64;
    for (int i = ty; i < 64; i += 4)
        tile[i][tx] = __float2bfloat16(in[(size_t)(by + i) * 1024 + bx + tx]);
    __syncthreads();
    for (int i = ty; i < 64; i += 4)
        out[(size_t)(bx + i) * 1024 + by + tx] = tile[tx][i];
}

// ---------------------------------------------------------------------------
// QKV projection GEMM. BK=64, single-buffered staging, 16 K-iterations
// (vs 32): the per-iter barrier forces a vmcnt(0) drain of staging latency —
// halving iteration count halves the exposed drains (dbuf cannot hide them:
// the barrier drains prefetch loads too; measured r5/r6).
// Tile 128x128, 4 waves x (64x64). A staged fp32 (cvt at frag read).
// XCD swizzle: 8 n-blocks sharing an A-tile land on one XCD.
// A row = 64 fp32 = 16 slots of 16B, swizzle slot^=(row&7);
// B row = 64 bf16 =  8 slots of 16B, swizzle slot^=(row&7).
// ---------------------------------------------------------------------------
__global__ __launch_bounds__(256, 3) void qkv_gemm(
    const float* __restrict__ Xq, const float* __restrict__ Xk,
    const float* __restrict__ Xv, const bf16* __restrict__ Wt_all,
    const float* __restrict__ bq, const float* __restrict__ bk,
    const float* __restrict__ bv,
    bf16* __restrict__ outq, bf16* __restrict__ outk, bf16* __restrict__ outv)
{
    __shared__ float As[128 * 64];   // 32KB
    __shared__ bf16  Bs[128 * 64];   // 16KB

    int wg = blockIdx.x;
    int xcd = wg & 7;
    int jj = wg >> 3;                  // 0..95
    int grp = xcd * 12 + (jj >> 3);    // 0..95
    int z = grp >> 5;                  // 0..2
    int m_blk = grp & 31;
    int n_blk = jj & 7;

    const float* X    = (z == 0) ? Xq : (z == 1) ? Xk : Xv;
    const float* bias = (z == 0) ? bq : (z == 1) ? bk : bv;
    const bf16*  Wt   = Wt_all + (size_t)z * 1048576;
    bf16*        out  = (z == 0) ? outq : (z == 1) ? outk : outv;
    bool vmode = (z == 2);

    int tid = threadIdx.x;
    int w = tid >> 6, lane = tid & 63, l16 = lane & 15, quad = lane >> 4;
    int m_base = m_blk * 128, n_base = n_blk * 128;

    // staging lane constants
    int r4 = lane >> 4, s16 = lane & 15;   // A: 4 rows x 16 slots per async16
    int r8 = lane >> 3, s8 = lane & 7;     // B: 8 rows x  8 slots per async16
    const float* Asrc0 = X + (size_t)(m_base + w * 32 + r4) * 1024 + ((s16 ^ r4) << 2);
    const float* Asrc1 = X + (size_t)(m_base + w * 32 + r4) * 1024 + ((s16 ^ (4 + r4)) << 2);
    const bf16*  Bsrc  = Wt + (size_t)(n_base + w * 32 + r8) * 1024 + ((s8 ^ r8) << 3);

    int wm = (w & 1) * 64, wn = (w >> 1) * 64;
    int sw = l16 & 7;

    float4v zero = {0.f, 0.f, 0.f, 0.f};
    float4v acc[4][4];
    #pragma unroll
    for (int mi = 0; mi < 4; ++mi)
        #pragma unroll
        for (int nj = 0; nj < 4; ++nj) acc[mi][nj] = zero;

    for (int it = 0; it < 16; ++it) {
        int kt = it * 64;
        #pragma unroll
        for (int p = 0; p < 8; ++p) {
            const float* s = ((p & 1) ? Asrc1 : Asrc0) + (size_t)p * 4096 + kt;
            async16(s, (char*)As + (w * 32 + p * 4) * 256);
        }
        #pragma unroll
        for (int p = 0; p < 4; ++p)
            async16(Bsrc + (size_t)p * 8192 + kt, (char*)Bs + (w * 32 + p * 8) * 128);
        __syncthreads();

        #pragma unroll
        for (int kk = 0; kk < 2; ++kk) {
            short8 af[4], bfr[4];
            #pragma unroll
            for (int mi = 0; mi < 4; ++mi) {
                const float* rp = As + (wm + mi * 16 + l16) * 64;
                float4 f0 = *(const float4*)(rp + (((kk * 8 + quad * 2)     ^ sw) << 2));
                float4 f1 = *(const float4*)(rp + (((kk * 8 + quad * 2 + 1) ^ sw) << 2));
                af[mi] = cvt8(f0, f1);
            }
            #pragma unroll
            for (int nj = 0; nj < 4; ++nj) {
                const bf16* rp = Bs + (wn + nj * 16 + l16) * 64;
                bfr[nj] = load8(rp + (((kk * 4 + quad) ^ sw) << 3));
            }
            #pragma unroll
            for (int mi = 0; mi < 4; ++mi)
                #pragma unroll
                for (int nj = 0; nj < 4; ++nj)
                    acc[mi][nj] = MFMA16(af[mi], bfr[nj], acc[mi][nj]);
        }
        __syncthreads();
    }

    float bsv[4];
    #pragma unroll
    for (int nj = 0; nj < 4; ++nj)
        bsv[nj] = bias[n_base + wn + nj * 16 + l16];

    #pragma unroll
    for (int mi = 0; mi < 4; ++mi) {
        #pragma unroll
        for (int nj = 0; nj < 4; ++nj) {
            int n = n_base + wn + nj * 16 + l16;
            int h = n >> 6, dk = n & 63;
            int m0 = m_base + wm + mi * 16 + quad * 4;
            int b = m0 >> 11, s0 = m0 & 2047;
            if (vmode) {
                float v0 = acc[mi][nj][0] + bsv[nj];
                float v1 = acc[mi][nj][1] + bsv[nj];
                float v2 = acc[mi][nj][2] + bsv[nj];
                float v3 = acc[mi][nj][3] + bsv[nj];
                uint2 pv; pv.x = pack2(v0, v1); pv.y = pack2(v2, v3);
                size_t idx = ((size_t)(b * 16 + h) * 64 + dk) * 2048 + s0;
                *reinterpret_cast<uint2*>(out + idx) = pv;
            } else {
                #pragma unroll
                for (int r = 0; r < 4; ++r) {
                    size_t idx = (((size_t)(b * 16 + h) * 2048 + s0 + r) * 64 + dk);
                    out[idx] = __float2bfloat16(acc[mi][nj][r] + bsv[nj]);
                }
            }
        }
    }
}

// ---------------------------------------------------------------------------
// Output projection: out[4096,1024] fp32 = A(bf16) @ Wo + bo.
// BK=64, single-buffer, 16 iters (16 MFMA/iter/wave vs 8: better
// compute-per-drain). Tile 128x64, grid 512, XCD swizzle.
// ---------------------------------------------------------------------------
__global__ __launch_bounds__(256, 2) void out_gemm(
    const bf16* __restrict__ A, const bf16* __restrict__ Wt,
    const float* __restrict__ bias, float* __restrict__ out)
{
    __shared__ bf16 As[128 * 64];   // 16KB
    __shared__ bf16 Bs[64 * 64];    // 8KB

    int wg = blockIdx.x;
    int xcd = wg & 7;
    int jj = wg >> 3;                  // 0..63
    int m_blk = xcd * 4 + (jj >> 4);   // 0..31
    int n_blk = jj & 15;

    int tid = threadIdx.x;
    int w = tid >> 6, lane = tid & 63, l16 = lane & 15, quad = lane >> 4;
    int m_base = m_blk * 128, n_base = n_blk * 64;

    int r8 = lane >> 3, s8 = lane & 7;
    const bf16* Asrc = A  + (size_t)(m_base + w * 32 + r8) * 1024 + ((s8 ^ r8) << 3);
    const bf16* Bsrc = Wt + (size_t)(n_base + w * 16 + r8) * 1024 + ((s8 ^ r8) << 3);

    int wm = (w & 1) * 64, wn = (w >> 1) * 32;
    int sw = l16 & 7;

    float4v zero = {0.f, 0.f, 0.f, 0.f};
    float4v acc[4][2];
    #pragma unroll
    for (int mi = 0; mi < 4; ++mi)
        #pragma unroll
        for (int nj = 0; nj < 2; ++nj) acc[mi][nj] = zero;

    for (int it = 0; it < 16; ++it) {
        int kt = it * 64;
        #pragma unroll
        for (int p = 0; p < 4; ++p)
            async16(Asrc + (size_t)p * 8192 + kt, (char*)As + (w * 32 + p * 8) * 128);
        #pragma unroll
        for (int p = 0; p < 2; ++p)
            async16(Bsrc + (size_t)p * 8192 + kt, (char*)Bs + (w * 16 + p * 8) * 128);
        __syncthreads();

        #pragma unroll
        for (int kk = 0; kk < 2; ++kk) {
            short8 af[4], bfr[2];
            #pragma unroll
            for (int mi = 0; mi < 4; ++mi) {
                const bf16* rp = As + (wm + mi * 16 + l16) * 64;
                af[mi] = load8(rp + (((kk * 4 + quad) ^ sw) << 3));
            }
            #pragma unroll
            for (int nj = 0; nj < 2; ++nj) {
                const bf16* rp = Bs + (wn + nj * 16 + l16) * 64;
                bfr[nj] = load8(rp + (((kk * 4 + quad) ^ sw) << 3));
            }
            #pragma unroll
            for (int mi = 0; mi < 4; ++mi)
                #pragma unroll
                for (int nj = 0; nj < 2; ++nj)
                    acc[mi][nj] = MFMA16(af[mi], bfr[nj], acc[mi][nj]);
        }
        __syncthreads();
    }

    float bsv[2];
    #pragma unroll
    for (int nj = 0; nj < 2; ++nj)
        bsv[nj] = bias[n_base + wn + nj * 16 + l16];

    #pragma unroll
    for (int mi = 0; mi < 4; ++mi)
        #pragma unroll
        for (int nj = 0; nj < 2; ++nj) {
            int n = n_base + wn + nj * 16 + l16;
            int m0 = m_base + wm + mi * 16 + quad * 4;
            #pragma unroll
            for (int r = 0; r < 4; ++r)
                out[(size_t)(m0 + r) * 1024 + n] = acc[mi][nj][r] + bsv[nj];
        }
}

// ---------------------------------------------------------------------------
// Flash attention, S-transposed. 128-key staged chunks, 16 iterations (half
// the barrier drains of r7's 64-key chunks); each chunk processed as two
// 64-key sub-passes from the same staged buffer (no barrier between —
// per-wave in-order DS covers the P round-trip).
// Block = 4 waves x 32 q; grid 512, XCD swizzle; ballot bitmask for mask.
// LDS: Kc 16KB [key][d] + Vc 16KB [d][key] + P 18KB + maskb = ~50KB.
// ---------------------------------------------------------------------------
__global__ __launch_bounds__(256, 3) void attn_fused(
    const bf16* __restrict__ Qm, const bf16* __restrict__ Km,
    const bf16* __restrict__ Vt, const int* __restrict__ mask,
    bf16* __restrict__ Oout)
{
    __shared__ __align__(16) bf16 Kc[128 * 64];    // 16KB [key 0..127][d]
    __shared__ __align__(16) bf16 Vc[64 * 128];    // 16KB [d][key 0..127]
    __shared__ __align__(16) bf16 P[4][32 * 72];   // 18KB per-wave P^T
    __shared__ unsigned long long maskb[32];       // bit k of [i] = mask[i*64+k]

    int tid = threadIdx.x;
    int w = tid >> 6, lane = tid & 63, l16 = lane & 15, quad = lane >> 4;
    int wg = blockIdx.x;
    int xcd = wg & 7;
    int jj = wg >> 3;                  // 0..63
    int bh = xcd * 4 + (jj >> 4);      // 0..31
    int qg = jj & 15;
    int b = bh >> 4, h = bh & 15;
    int tile0 = (qg * 4 + w) * 2;

    // ballot bitmask: wave w covers keys w*512 .. w*512+511
    const int* mb = mask + b * 2048;
    #pragma unroll
    for (int i = 0; i < 8; ++i) {
        unsigned long long bal = __ballot(mb[w * 512 + i * 64 + lane] != 0);
        if (lane == 0) maskb[w * 8 + i] = bal;
    }

    short8 bQ[2][2];
    #pragma unroll
    for (int qi = 0; qi < 2; ++qi) {
        const bf16* Qb = Qm + ((size_t)bh * 2048 + (size_t)(tile0 + qi) * 16) * 64;
        bQ[qi][0] = load8(Qb + l16 * 64 + quad * 8);
        bQ[qi][1] = load8(Qb + l16 * 64 + 32 + quad * 8);
    }

    // staging lane constants
    int r8 = lane >> 3, s8 = lane & 7;     // K: 8 rows x 8 slots per async16
    int r4 = lane >> 4, s16 = lane & 15;   // V: 4 rows x 16 slots per async16
    const bf16* Ksrc  = Km + (size_t)bh * 131072 + (size_t)(w * 32 + r8) * 64 + ((s8 ^ r8) << 3);
    const bf16* Vsrc0 = Vt + (size_t)bh * 131072 + (size_t)(w * 16 + r4) * 2048 + ((s16 ^ r4) << 3);
    const bf16* Vsrc1 = Vt + (size_t)bh * 131072 + (size_t)(w * 16 + r4) * 2048 + ((s16 ^ (4 + r4)) << 3);

    bf16* Pw = &P[w][0];
    int sw = l16 & 7;

    float4v zero = {0.f, 0.f, 0.f, 0.f};
    float4v Oacc[2][4];
    #pragma unroll
    for (int qi = 0; qi < 2; ++qi)
        #pragma unroll
        for (int g = 0; g < 4; ++g) Oacc[qi][g] = zero;
    float lsum[2] = {0.f, 0.f};
    const float C = 0.18033688f;                   // log2(e)/8

    for (int it = 0; it < 16; ++it) {
        int kt = it * 128;
        // stage 128 keys: K 4 async/wave, V 4 async/wave
        #pragma unroll
        for (int p = 0; p < 4; ++p)
            async16(Ksrc + (size_t)(kt + p * 8) * 64, (char*)Kc + (w * 32 + p * 8) * 128);
        #pragma unroll
        for (int p = 0; p < 4; ++p) {
            const bf16* s = ((p & 1) ? Vsrc1 : Vsrc0) + (size_t)p * 8192 + kt;
            async16(s, (char*)Vc + (w * 16 + p * 4) * 256);
        }
        __syncthreads();   // staging landed (also publishes maskb on it==0)

        #pragma unroll
        for (int hh = 0; hh < 2; ++hh) {
            unsigned long long m64 = maskb[it * 2 + hh];
            bool full = (m64 == ~0ull);

            // --- S^T = K Q^T : 4 key-tiles x 2 q-tiles ---
            float4v S[2][4];
            #pragma unroll
            for (int kj = 0; kj < 4; ++kj) {
                const bf16* kr = Kc + (hh * 64 + kj * 16 + l16) * 64;
                short8 a0 = load8(kr + (((0 + quad) ^ sw) << 3));
                short8 a1 = load8(kr + (((4 + quad) ^ sw) << 3));
                #pragma unroll
                for (int qi = 0; qi < 2; ++qi) {
                    float4v s = zero;
                    s = MFMA16(a0, bQ[qi][0], s);
                    s = MFMA16(a1, bQ[qi][1], s);
                    S[qi][kj] = s;
                }
            }

            // --- p = exp2(S*C), mask-zero, key-sum per lane, P^T -> LDS ---
            #pragma unroll
            for (int kj = 0; kj < 4; ++kj) {
                unsigned m4 = (unsigned)(m64 >> (kj * 16 + quad * 4)) & 0xFu;
                #pragma unroll
                for (int qi = 0; qi < 2; ++qi) {
                    float p[4];
                    #pragma unroll
                    for (int r = 0; r < 4; ++r)
                        p[r] = __builtin_amdgcn_exp2f(S[qi][kj][r] * C);
                    if (!full) {
                        #pragma unroll
                        for (int r = 0; r < 4; ++r)
                            p[r] = ((m4 >> r) & 1u) ? p[r] : 0.f;
                    }
                    lsum[qi] += (p[0] + p[1]) + (p[2] + p[3]);
                    uint2 pw; pw.x = pack2(p[0], p[1]); pw.y = pack2(p[2], p[3]);
                    *reinterpret_cast<uint2*>(
                        &Pw[(qi * 16 + l16) * 72 + kj * 16 + quad * 4]) = pw;
                }
            }

            // --- O += P V ---
            short8 ap[2][2];
            #pragma unroll
            for (int qi = 0; qi < 2; ++qi) {
                ap[qi][0] = load8(&Pw[(qi * 16 + l16) * 72 + quad * 8]);
                ap[qi][1] = load8(&Pw[(qi * 16 + l16) * 72 + 32 + quad * 8]);
            }
            #pragma unroll
            for (int g = 0; g < 4; ++g) {
                const bf16* vr = Vc + (g * 16 + l16) * 128;
                short8 v0 = load8(vr + (((hh * 8 + 0 + quad) ^ sw) << 3));
                short8 v1 = load8(vr + (((hh * 8 + 4 + quad) ^ sw) << 3));
                #pragma unroll
                for (int qi = 0; qi < 2; ++qi) {
                    Oacc[qi][g] = MFMA16(ap[qi][0], v0, Oacc[qi][g]);
                    Oacc[qi][g] = MFMA16(ap[qi][1], v1, Oacc[qi][g]);
                }
            }
        }
        __syncthreads();   // all waves done reading Kc/Vc before next stage
    }

    #pragma unroll
    for (int qi = 0; qi < 2; ++qi) {
        float ls = lsum[qi];
        ls += __shfl_xor(ls, 16, 64);
        ls += __shfl_xor(ls, 32, 64);
        #pragma unroll
        for (int r = 0; r < 4; ++r) {
            float linv = 1.f / __shfl(ls, quad * 4 + r, 64);
            int srow = (tile0 + qi) * 16 + quad * 4 + r;
            size_t base = ((size_t)b * 2048 + srow) * 1024 + h * 64;
            #pragma unroll
            for (int g = 0; g < 4; ++g)
                Oout[base + g * 16 + l16] = __float2bfloat16(Oacc[qi][g][r] * linv);
        }
    }
}

// ---------------------------------------------------------------------------
// Workspace (16 MB of d_ws; d_out doubles as scratch):
//   ws[ 0.. 8): vb [B,H,Dk,S]          -> then Wo^T at [0..2) after attn
//   ws[ 8..14): Wq^T, Wk^T, Wv^T (dead after qkv_gemm)
//   ws[ 8..16): aout [B,S,1024] bf16 (over dead Wq/k/v^T)
//   d_out[0..8): qb, [8..16): kb (dead before out_gemm overwrites d_out)
// ---------------------------------------------------------------------------
extern "C" void kernel_launch(void* const* d_in, const int* in_sizes, int n_in,
                              void* d_out, int out_size, void* d_ws, size_t ws_size,
                              hipStream_t stream) {
    const float* query = (const float*)d_in[0];
    const float* key   = (const float*)d_in[1];
    const float* value = (const float*)d_in[2];
    const int*   mask  = (const int*)d_in[3];
    const float* Wq = (const float*)d_in[4];
    const float* bq = (const float*)d_in[5];
    const float* Wk = (const float*)d_in[6];
    const float* bk = (const float*)d_in[7];
    const float* Wv = (const float*)d_in[8];
    const float* bv = (const float*)d_in[9];
    const float* Wo = (const float*)d_in[10];
    const float* bo = (const float*)d_in[11];

    char* ws = (char*)d_ws;
    const size_t MB = 1024 * 1024;
    bf16* vb     = (bf16*)ws;                 // 8 MB
    bf16* Wt_all = (bf16*)(ws + 8 * MB);      // 3 x 2 MB
    bf16* aout   = (bf16*)(ws + 8 * MB);      // 8 MB (after Wq/k/v^T dead)
    bf16* WtO    = (bf16*)ws;                 // 2 MB (after vb dead)
    bf16* qb     = (bf16*)d_out;
    bf16* kb     = (bf16*)((char*)d_out + 8 * MB);
    float* out   = (float*)d_out;

    transpose_qkv<<<dim3(16, 16, 3), dim3(64, 4), 0, stream>>>(Wq, Wk, Wv, Wt_all);

    qkv_gemm<<<dim3(768), 256, 0, stream>>>(
        query, key, value, Wt_all, bq, bk, bv, qb, kb, vb);

    attn_fused<<<dim3(512), 256, 0, stream>>>(qb, kb, vb, mask, aout);

    transpose_one<<<dim3(16, 16), dim3(64, 4), 0, stream>>>(Wo, WtO);

    out_gemm<<<dim3(512), 256, 0, stream>>>(aout, WtO, bo, out);
}